// Round 14
// baseline (165.500 us; speedup 1.0000x reference)
//
#include <hip/hip_runtime.h>

// Attention_73375221285454: fused MHA block on MI355X (gfx950)
// B=4 N=2048 D=768 H=12 DH=64. fp32 in/out, bf16 MFMA internally.
// Round 14: ONE change vs r13 — k_attn gets an XCD-pinned block decode:
// xcd=f&7, bh=(f>>3 / 16)*8+xcd, qt=(f>>3)&15. All q-tiles of a bh run on
// ONE XCD consecutively -> its 256KB K/V stays L2-resident (r13 counters:
// attn FETCH 55MB vs ~18MB unique = 4-8x K/V re-fetch across XCDs; STAGE
// misses to HBM ~900cyc defeat the 1-barrier pipeline). Rest = r13.

#define B_ 4
#define N_ 2048
#define D_ 768
#define H_ 12
#define DH_ 64
#define CSC_ 0.18033688011112042f  // SCALE * log2(e)

typedef __attribute__((ext_vector_type(8))) short bf8_t;   // 8 bf16 (MFMA A/B frag)
typedef __attribute__((ext_vector_type(4))) float f4_t;    // 16x16 C/D frag
typedef __attribute__((ext_vector_type(16))) float f16v;   // 32x32 C/D frag
typedef __attribute__((ext_vector_type(4))) int i4_t;

__device__ __forceinline__ short f2b(float f) {            // fp32 -> bf16 RNE
  union { float f; unsigned u; } v; v.f = f;
  unsigned r = v.u + 0x7FFFu + ((v.u >> 16) & 1u);
  return (short)(r >> 16);
}
__device__ __forceinline__ unsigned cvtpk(float lo, float hi) {
  unsigned r;
  asm("v_cvt_pk_bf16_f32 %0, %1, %2" : "=v"(r) : "v"(lo), "v"(hi));
  return r;
}
__device__ __forceinline__ void plswap(unsigned& a, unsigned& b) {
  asm("v_permlane32_swap_b32 %0, %1" : "+v"(a), "+v"(b));
}
__device__ __forceinline__ float max3f(float a, float b, float c) {
  float r;
  asm("v_max3_f32 %0, %1, %2, %3" : "=v"(r) : "v"(a), "v"(b), "v"(c));
  return r;
}

#define GLOAD_LDS16(gp, lp)                                                       \
  __builtin_amdgcn_global_load_lds(                                               \
      (const __attribute__((address_space(1))) void*)(gp),                        \
      (__attribute__((address_space(3))) void*)(lp), 16, 0, 0)

// ------- per-batch valid-index list + inverse perm pos[n] -------
__global__ __launch_bounds__(256) void k_maskidx(const int* __restrict__ xmask,
                                                 int* __restrict__ idx,
                                                 int* __restrict__ pos,
                                                 int* __restrict__ cnt) {
  int b = blockIdx.x, t = threadIdx.x;
  const int* mp = xmask + b * N_;
  int c = 0;
#pragma unroll
  for (int j = 0; j < 8; ++j) c += (mp[t * 8 + j] != 0);
  __shared__ int sc[256];
  sc[t] = c;
  __syncthreads();
  for (int off = 1; off < 256; off <<= 1) {
    int v = (t >= off) ? sc[t - off] : 0;
    __syncthreads();
    sc[t] += v;
    __syncthreads();
  }
  int p = sc[t] - c;
#pragma unroll
  for (int j = 0; j < 8; ++j) {
    int n = t * 8 + j;
    int v = mp[n];
    pos[b * N_ + n] = v ? p : -1;
    if (v) { idx[b * N_ + p] = n; ++p; }
  }
  if (t == 255) cnt[b] = sc[255];
}

// ------- fused: column partial-sums of x + gather valid rows -> bf16 xc -------
__global__ __launch_bounds__(256) void k_gxsum(const float* __restrict__ x,
                                               const int* __restrict__ pos,
                                               const int* __restrict__ cnt,
                                               float* __restrict__ xpart,
                                               short* __restrict__ xc) {
  int b = blockIdx.y, ch = blockIdx.x, t = threadIdx.x;
  if (ch == 64) {
    int cn = cnt[b], cnpad = (cn + 127) & ~127;
    int nel = (cnpad - cn) * D_;
    short* base = xc + ((size_t)b * N_ + cn) * D_;
    const bf8_t zz = {0, 0, 0, 0, 0, 0, 0, 0};
    for (int i = t * 8; i < nel; i += 256 * 8) *(bf8_t*)(base + i) = zz;
    return;
  }
  const float* xp = x + ((size_t)b * N_ + ch * 32) * D_;
  const int* pp = pos + b * N_ + ch * 32;
  float a0 = 0, a1 = 0, a2 = 0;
  for (int r = 0; r < 32; ++r) {
    const float* rp = xp + (size_t)r * D_;
    float v0 = rp[t], v1 = rp[t + 256], v2 = rp[t + 512];
    a0 += v0; a1 += v1; a2 += v2;
    int p = pp[r];
    if (p >= 0) {
      short* op = xc + ((size_t)b * N_ + p) * D_;
      op[t] = f2b(v0); op[t + 256] = f2b(v1); op[t + 512] = f2b(v2);
    }
  }
  float* op2 = xpart + ((size_t)b * 64 + ch) * D_;
  op2[t] = a0; op2[t + 256] = a1; op2[t + 512] = a2;
}

// ------- xmean[b][c] = (1/2048) sum_ch xpart[b][ch][c] -------
__global__ __launch_bounds__(256) void k_xmean(const float* __restrict__ xpart,
                                               float* __restrict__ xmean) {
  int b = blockIdx.y;
  int col = blockIdx.x * 64 + (threadIdx.x & 63);
  int grp = threadIdx.x >> 6;
  float s = 0;
#pragma unroll
  for (int i = 0; i < 16; ++i)
    s += xpart[((size_t)b * 64 + grp * 16 + i) * D_ + col];
  __shared__ float red[4][64];
  red[grp][threadIdx.x & 63] = s;
  __syncthreads();
  if (grp == 0) {
    int cl = threadIdx.x & 63;
    xmean[b * D_ + col] = (red[0][cl] + red[1][cl] + red[2][cl] + red[3][cl]) * (1.f / 2048.f);
  }
}

// ------- y[b][col] = sum_k xv[b][k] * W[k][col]  (split-k GEMV) -------
__global__ __launch_bounds__(256) void k_gemv(const float* __restrict__ xv,
                                              const float* __restrict__ W,
                                              float* __restrict__ y) {
  int b = blockIdx.y;
  int cl = threadIdx.x & 63;
  int col = blockIdx.x * 64 + cl;
  int grp = threadIdx.x >> 6;
  __shared__ float xs[768];
  for (int c = threadIdx.x; c < 768; c += 256) xs[c] = xv[b * D_ + c];
  __syncthreads();
  float acc = 0;
  const float* wp = W + (size_t)(grp * 192) * D_ + col;
  const float* xp = xs + grp * 192;
#pragma unroll 4
  for (int k = 0; k < 192; ++k) acc += xp[k] * wp[(size_t)k * D_];
  __shared__ float red[4][64];
  red[grp][cl] = acc;
  __syncthreads();
  if (grp == 0) y[b * D_ + col] = red[0][cl] + red[1][cl] + red[2][cl] + red[3][cl];
}

// ------- prep: transpose weights fp32->bf16 into B^T layout; Wq pre-scaled -------
__global__ __launch_bounds__(256) void k_wtrans(const float* __restrict__ Wq,
                                                const float* __restrict__ Wk,
                                                const float* __restrict__ Wv,
                                                const float* __restrict__ Wo,
                                                short* __restrict__ WqkvT,
                                                short* __restrict__ WoT) {
  int z = blockIdx.z;
  const float* W = (z == 0) ? Wq : (z == 1) ? Wk : (z == 2) ? Wv : Wo;
  short* dst = (z < 3) ? (WqkvT + (size_t)z * D_ * D_) : WoT;
  float sc = (z == 0) ? CSC_ : 1.f;
  __shared__ float T[64][65];
  int r0 = blockIdx.y * 64, c0 = blockIdx.x * 64;
  int tr = threadIdx.x >> 6, tc = threadIdx.x & 63;
#pragma unroll
  for (int i = 0; i < 16; ++i) {
    int r = tr + i * 4;
    T[r][tc] = W[(size_t)(r0 + r) * D_ + c0 + tc];
  }
  __syncthreads();
#pragma unroll
  for (int i = 0; i < 16; ++i) {
    int r = tr + i * 4;
    dst[(size_t)(c0 + r) * D_ + r0 + tc] = f2b(T[tc][r] * sc);
  }
}

// ------- GEMM: dense-active remap + col-fast m204 XCD swizzle + gload_lds dbuf -------
template <int MODE>
__global__ __launch_bounds__(256) void k_gemm(const short* __restrict__ A,
                                              const short* __restrict__ BT, int K,
                                              short* __restrict__ Qb, short* __restrict__ Kb,
                                              short* __restrict__ Vb,
                                              float* __restrict__ Cout, int ldc,
                                              const int* __restrict__ cnt,
                                              const int* __restrict__ idx) {
  __shared__ short As[2][128 * 64];
  __shared__ short Bs[2][128 * 64];
  int n0t = (cnt[0] + 127) >> 7, n1t = (cnt[1] + 127) >> 7;
  int n2t = (cnt[2] + 127) >> 7, n3t = (cnt[3] + 127) >> 7;
  int p1 = n0t, p2 = p1 + n1t, p3 = p2 + n2t;
  int T = p3 + n3t;
  int gcols = gridDim.x;
  int Tg = T * gcols;
  int f = blockIdx.y * gcols + blockIdx.x;
  if (f >= Tg) return;
  int q = Tg >> 3, rm = Tg & 7;
  int xcd = f & 7, kch = f >> 3;
  int s = (xcd < rm ? xcd * (q + 1) : rm * (q + 1) + (xcd - rm) * q) + kch;
  int row_a = s / gcols;
  int colt = s - row_a * gcols;
  int b = (row_a >= p1) + (row_a >= p2) + (row_a >= p3);
  int pref = (b == 0) ? 0 : (b == 1) ? p1 : (b == 2) ? p2 : p3;
  int row0 = (b << 11) + ((row_a - pref) << 7);
  int col0 = colt << 7;
  int cn = cnt[b];

  int tid = threadIdx.x, lane = tid & 63, w = tid >> 6;
  int wr = w >> 1, wc = w & 1;
  int lr = lane & 15, lhi = lane >> 4;
  f4_t acc[4][4];
#pragma unroll
  for (int mi = 0; mi < 4; ++mi)
#pragma unroll
    for (int ni = 0; ni < 4; ++ni) acc[mi][ni] = (f4_t){0.f, 0.f, 0.f, 0.f};

  int sub = lane >> 3;
  int scb = ((lane & 7) * 16) ^ (sub << 4);
  auto STAGE = [&](int k0, int buf) {
    char* ab = (char*)As[buf] + (w << 12);
    char* bb2 = (char*)Bs[buf] + (w << 12);
#pragma unroll
    for (int i = 0; i < 4; ++i) {
      int r = 32 * w + 8 * i + sub;
      GLOAD_LDS16((const char*)(A + (size_t)(row0 + r) * K + k0) + scb, ab + (i << 10));
      GLOAD_LDS16((const char*)(BT + (size_t)(col0 + r) * K + k0) + scb, bb2 + (i << 10));
    }
  };

  STAGE(0, 0);

  int nt = K / 64;
  for (int t = 0; t < nt; ++t) {
    int cur = t & 1;
    if (t + 1 < nt) {
      STAGE((t + 1) * 64, cur ^ 1);
      asm volatile("s_waitcnt vmcnt(8)" ::: "memory");
    } else {
      asm volatile("s_waitcnt vmcnt(0)" ::: "memory");
    }
    __builtin_amdgcn_sched_barrier(0);
    __builtin_amdgcn_s_barrier();

    const char* Ac = (const char*)As[cur];
    const char* Bc = (const char*)Bs[cur];
    int rsw = (lr & 7) << 4;
#pragma unroll
    for (int kc = 0; kc < 2; ++kc) {
      bf8_t av[4], bv[4];
#pragma unroll
      for (int mi = 0; mi < 4; ++mi) {
        int row = 64 * wr + 16 * mi + lr;
        av[mi] = *(const bf8_t*)(Ac + row * 128 + ((64 * kc + 16 * lhi) ^ rsw));
      }
#pragma unroll
      for (int ni = 0; ni < 4; ++ni) {
        int row = 64 * wc + 16 * ni + lr;
        bv[ni] = *(const bf8_t*)(Bc + row * 128 + ((64 * kc + 16 * lhi) ^ rsw));
      }
#pragma unroll
      for (int mi = 0; mi < 4; ++mi)
#pragma unroll
        for (int ni = 0; ni < 4; ++ni)
          acc[mi][ni] = __builtin_amdgcn_mfma_f32_16x16x32_bf16(av[mi], bv[ni], acc[mi][ni], 0, 0, 0);
    }
    __builtin_amdgcn_sched_barrier(0);
    __builtin_amdgcn_s_barrier();
  }

#pragma unroll
  for (int mi = 0; mi < 4; ++mi)
#pragma unroll
    for (int ni = 0; ni < 4; ++ni)
#pragma unroll
      for (int r = 0; r < 4; ++r) {
        int row = row0 + 64 * wr + 16 * mi + 4 * lhi + r;
        int col = col0 + 64 * wc + 16 * ni + lr;
        float v = acc[mi][ni][r];
        if (MODE == 0) {
          int which = col / 768;
          int cc2 = col - which * 768;
          int h = cc2 >> 6, dh = cc2 & 63;
          int bb = row >> 11, n = row & 2047;
          size_t dst = (((size_t)(bb * H_ + h)) * N_ + n) * DH_ + dh;
          short bv2 = f2b(v);
          if (which == 0) Qb[dst] = bv2;
          else if (which == 1) Kb[dst] = bv2;
          else Vb[dst] = bv2;
        } else {
          int j = row & 2047;
          if (j < cn) {
            int n = idx[(row & ~2047) + j];
            Cout[((size_t)(row & ~2047) + n) * ldc + col] = v;
          }
        }
      }
}

// ---------------- Vc[bh][j][dh] -> Vtc[bh][dh][j] (compacted) ----------------
__global__ __launch_bounds__(256) void k_vtrans(const short* __restrict__ V,
                                                const int* __restrict__ cnt,
                                                short* __restrict__ Vt) {
  int bh = blockIdx.y, b = bh / H_;
  int n0 = blockIdx.x * 64;
  int cn = cnt[b];
  int cnpad = (cn + 127) & ~127;
  if (n0 >= cnpad) return;
  __shared__ short T[64][72];
  int tr = threadIdx.x >> 6, tc = threadIdx.x & 63;
  const short* Vp = V + (size_t)bh * N_ * DH_;
  short* Vtp = Vt + (size_t)bh * DH_ * N_;
#pragma unroll
  for (int i = 0; i < 16; ++i) {
    int r = tr + i * 4;
    T[r][tc] = Vp[(size_t)(n0 + r) * DH_ + tc];
  }
  __syncthreads();
#pragma unroll
  for (int i = 0; i < 16; ++i) {
    int r = tr + i * 4;
    Vtp[(size_t)r * N_ + n0 + tc] = T[tc][r];
  }
}

// -------- fill masked rows of out with outrow[b] (fp32) --------
__global__ __launch_bounds__(256) void k_fillout(const int* __restrict__ xmask,
                                                 const float* __restrict__ outrowG,
                                                 float* __restrict__ out) {
  int b = blockIdx.y;
  int n = blockIdx.x * 32 + (threadIdx.x >> 3);
  int cg = threadIdx.x & 7;
  if (xmask[b * N_ + n]) return;
  const float* rp = outrowG + b * D_;
  float* op = out + ((size_t)b * N_ + n) * D_;
#pragma unroll
  for (int it = 0; it < 12; ++it) {
    int c = cg * 8 + it * 64;
    float4 v0 = *(const float4*)(rp + c);
    float4 v1 = *(const float4*)(rp + c + 4);
    *(float4*)(op + c) = v0;
    *(float4*)(op + c + 4) = v1;
  }
}

// -------- flash attention on compacted q/k; bh pinned to one XCD (T1) --------
__global__ __launch_bounds__(256, 3) void k_attn(const short* __restrict__ Q,
                                                 const short* __restrict__ Kcg,
                                                 const short* __restrict__ Vtcg,
                                                 const int* __restrict__ cnt,
                                                 short* __restrict__ Aout) {
  // XCD-pinned decode: xcd = f&7; 6 bh per XCD, q-tiles consecutive per bh.
  int f = blockIdx.y * gridDim.x + blockIdx.x;   // 0..767
  int xcd = f & 7, loc = f >> 3;                 // loc 0..95
  int bh = (loc >> 4) * 8 + xcd;                 // 0..47
  int qt = loc & 15;
  int b = bh / H_, h = bh - b * H_;
  int cn = cnt[b];
  int nqt = (cn + 127) >> 7;
  if (qt >= nqt) return;                         // balanced exits per XCD
  int nkt = (cn + 63) >> 6;
  const short* Qp = Q + (size_t)bh * N_ * DH_;
  const short* Kp = Kcg + (size_t)bh * N_ * DH_;
  const short* Vp = Vtcg + (size_t)bh * DH_ * N_;
  int q0 = qt * 128;
  int tid = threadIdx.x, lane = tid & 63, w = tid >> 6;
  int lq = lane & 31, hi = lane >> 5;

  __shared__ char smem[32768];

  int qrow = q0 + 32 * w + lq;

  bf8_t qf[4];
#pragma unroll
  for (int kc = 0; kc < 4; ++kc)
    qf[kc] = *(const bf8_t*)(Qp + (size_t)qrow * DH_ + 16 * kc + 8 * hi);

  short NEGBIG = f2b(-1e30f);
  bf8_t qbf = {hi ? (short)0 : (short)0x3F80, 0, 0, 0, 0, 0, 0, 0};

  f16v acco[2];
#pragma unroll
  for (int i = 0; i < 16; ++i) { acco[0][i] = 0.f; acco[1][i] = 0.f; }
  float m = -1e29f, lsum = 0.f;

  auto STAGE = [&](int key0, int buf) {
    char* kb_ = smem + buf * 16384;
    char* vb_ = kb_ + 8192;
    int row = tid >> 3;
    int cb = (tid & 7) * 16;
    char* lk = kb_ + ((tid >> 6) << 10);
    char* lv = vb_ + ((tid >> 6) << 10);
#pragma unroll
    for (int rr = 0; rr < 2; ++rr) {
      int r2 = row + rr * 32;
      int sw = cb ^ ((r2 & 7) << 4);
      GLOAD_LDS16((const char*)(Kp + (size_t)(key0 + r2) * DH_) + sw, lk + rr * 4096);
      GLOAD_LDS16((const char*)(Vp + (size_t)r2 * N_ + key0) + sw, lv + rr * 4096);
    }
  };

  STAGE(0, 0);
  __syncthreads();

  for (int kt = 0; kt < nkt; ++kt) {
    int cur = kt & 1;
    if (kt + 1 < nkt) STAGE((kt + 1) * 64, cur ^ 1);

    const char* kbase = smem + cur * 16384;
    const char* vbase = kbase + 8192;
    int key0 = kt * 64;

    f16v accs[2];
#pragma unroll
    for (int i = 0; i < 16; ++i) { accs[0][i] = 0.f; accs[1][i] = 0.f; }
    int swz = (lq & 7) << 4;
    __builtin_amdgcn_s_setprio(1);
#pragma unroll
    for (int kc = 0; kc < 4; ++kc) {
      int colb = (32 * kc + 16 * hi) ^ swz;
      bf8_t k0 = *(const bf8_t*)(kbase + lq * 128 + colb);
      bf8_t k1 = *(const bf8_t*)(kbase + (32 + lq) * 128 + colb);
      accs[0] = __builtin_amdgcn_mfma_f32_32x32x16_bf16(k0, qf[kc], accs[0], 0, 0, 0);
      accs[1] = __builtin_amdgcn_mfma_f32_32x32x16_bf16(k1, qf[kc], accs[1], 0, 0, 0);
    }
    __builtin_amdgcn_s_setprio(0);
    if (key0 + 64 > cn) {
      bf8_t bf0 = {(hi || key0 + lq < cn) ? (short)0 : NEGBIG, 0, 0, 0, 0, 0, 0, 0};
      bf8_t bf1 = {(hi || key0 + 32 + lq < cn) ? (short)0 : NEGBIG, 0, 0, 0, 0, 0, 0, 0};
      accs[0] = __builtin_amdgcn_mfma_f32_32x32x16_bf16(bf0, qbf, accs[0], 0, 0, 0);
      accs[1] = __builtin_amdgcn_mfma_f32_32x32x16_bf16(bf1, qbf, accs[1], 0, 0, 0);
    }

    float mx = max3f(accs[0][0], accs[0][1], accs[0][2]);
#pragma unroll
    for (int i = 3; i < 15; i += 2) mx = max3f(mx, accs[0][i], accs[0][i + 1]);
    mx = max3f(mx, accs[0][15], accs[1][0]);
#pragma unroll
    for (int i = 1; i < 15; i += 2) mx = max3f(mx, accs[1][i], accs[1][i + 1]);
    mx = fmaxf(mx, accs[1][15]);
    mx = fmaxf(mx, __shfl_xor(mx, 32));
    if (!__all(mx <= m + 8.f)) {
      float mnew = fmaxf(m, mx);
      float sc = __builtin_amdgcn_exp2f(m - mnew);
      m = mnew;
      lsum *= sc;
#pragma unroll
      for (int i = 0; i < 16; ++i) { acco[0][i] *= sc; acco[1][i] *= sc; }
    }
    float psa[4] = {0.f, 0.f, 0.f, 0.f};
#pragma unroll
    for (int kb2 = 0; kb2 < 2; ++kb2)
#pragma unroll
      for (int r = 0; r < 16; ++r) {
        float p = __builtin_amdgcn_exp2f(accs[kb2][r] - m);
        accs[kb2][r] = p;
        psa[r & 3] += p;
      }
    float ps = (psa[0] + psa[1]) + (psa[2] + psa[3]);
    ps += __shfl_xor(ps, 32);
    lsum += ps;

    __builtin_amdgcn_s_setprio(1);
#pragma unroll
    for (int kc = 0; kc < 4; ++kc) {
      int kb2 = kc >> 1, rb = (kc & 1) * 8;
      unsigned a_ = cvtpk(accs[kb2][rb + 0], accs[kb2][rb + 1]);
      unsigned b_ = cvtpk(accs[kb2][rb + 4], accs[kb2][rb + 5]);
      unsigned c_ = cvtpk(accs[kb2][rb + 2], accs[kb2][rb + 3]);
      unsigned d_ = cvtpk(accs[kb2][rb + 6], accs[kb2][rb + 7]);
      plswap(a_, b_);
      plswap(c_, d_);
      union { i4_t i; bf8_t v; } pu;
      pu.i = (i4_t){(int)a_, (int)c_, (int)b_, (int)d_};
      int colb = (32 * kc + 16 * hi) ^ swz;
      bf8_t v0 = *(const bf8_t*)(vbase + lq * 128 + colb);
      bf8_t v1 = *(const bf8_t*)(vbase + (32 + lq) * 128 + colb);
      acco[0] = __builtin_amdgcn_mfma_f32_32x32x16_bf16(v0, pu.v, acco[0], 0, 0, 0);
      acco[1] = __builtin_amdgcn_mfma_f32_32x32x16_bf16(v1, pu.v, acco[1], 0, 0, 0);
    }
    __builtin_amdgcn_s_setprio(0);

    __syncthreads();
  }
  __syncthreads();

  float inv = 1.f / lsum;
  unsigned* Os = (unsigned*)smem + w * 1152;
#pragma unroll
  for (int dhb = 0; dhb < 2; ++dhb)
#pragma unroll
    for (int r = 0; r < 16; r += 2) {
      unsigned pk = cvtpk(acco[dhb][r] * inv, acco[dhb][r + 1] * inv);
      int colu = 16 * dhb + ((r & 3) >> 1) + 4 * (r >> 2) + 2 * hi;
      Os[lq * 36 + colu] = pk;
    }
#pragma unroll
  for (int it = 0; it < 4; ++it) {
    int qq = (lane >> 3) + 8 * it;
    int qr2 = q0 + 32 * w + qq;
    if (qr2 < cn) {
      i4_t vv = *(const i4_t*)(Os + qq * 36 + 4 * (lane & 7));
      union { i4_t i; bf8_t s; } u2;
      u2.i = vv;
      size_t off = ((size_t)b * N_ + qr2) * D_ + h * DH_ + 8 * (lane & 7);
      *(bf8_t*)(Aout + off) = u2.s;
    }
  }
}

extern "C" void kernel_launch(void* const* d_in, const int* in_sizes, int n_in,
                              void* d_out, int out_size, void* d_ws, size_t ws_size,
                              hipStream_t stream) {
  (void)in_sizes; (void)n_in; (void)out_size; (void)ws_size;
  const float* x  = (const float*)d_in[0];
  const int*   xm = (const int*)d_in[1];
  const float* Wq = (const float*)d_in[2];
  const float* Wk = (const float*)d_in[3];
  const float* Wv = (const float*)d_in[4];
  const float* Wo = (const float*)d_in[5];
  float* out = (float*)d_out;
  char* ws = (char*)d_ws;

  short* xc      = (short*)(ws + 0);
  short* Ao      = (short*)(ws + 0);
  short* WqkvT   = (short*)(ws + 12582912);
  short* WoT     = (short*)(ws + 16121856);
  int*   idxb    = (int*)(ws + 17301504);
  int*   cntb    = (int*)(ws + 17334272);
  float* xpart   = (float*)(ws + 17334528);
  float* vmeanG  = (float*)(ws + 18120960);
  float* outrowG = (float*)(ws + 18133248);
  float* xmeanG  = (float*)(ws + 18145536);
  int*   posb    = (int*)(ws + 18157824);
  short* Qb      = (short*)(ws + 18874368);
  short* Kc      = (short*)(ws + 31457280);
  short* Vc      = (short*)(ws + 44040192);
  short* Vtc     = (short*)(ws + 56623104);

  k_maskidx<<<4, 256, 0, stream>>>(xm, idxb, posb, cntb);
  k_gxsum<<<dim3(65, 4), 256, 0, stream>>>(x, posb, cntb, xpart, xc);
  k_wtrans<<<dim3(12, 12, 4), 256, 0, stream>>>(Wq, Wk, Wv, Wo, WqkvT, WoT);
  k_gemm<0><<<dim3(18, 64), 256, 0, stream>>>(xc, WqkvT, 768, Qb, Kc, Vc,
                                              nullptr, 0, cntb, nullptr);
  k_vtrans<<<dim3(32, 48), 256, 0, stream>>>(Vc, cntb, Vtc);
  k_xmean<<<dim3(12, 4), 256, 0, stream>>>(xpart, xmeanG);
  k_gemv<<<dim3(12, 4), 256, 0, stream>>>(xmeanG, Wv, vmeanG);
  k_gemv<<<dim3(12, 4), 256, 0, stream>>>(vmeanG, Wo, outrowG);
  k_attn<<<dim3(16, 48), 256, 0, stream>>>(Qb, Kc, Vtc, cntb, Ao);
  k_fillout<<<dim3(64, 4), 256, 0, stream>>>(xm, outrowG, out);
  k_gemm<1><<<dim3(6, 64), 256, 0, stream>>>(Ao, WoT, 768, nullptr, nullptr, nullptr,
                                             out, 768, cntb, idxb);
}

// Round 15
// 157.982 us; speedup vs baseline: 1.0476x; 1.0476x over previous
//
#include <hip/hip_runtime.h>

// Attention_73375221285454: fused MHA block on MI355X (gfx950)
// B=4 N=2048 D=768 H=12 DH=64. fp32 in/out, bf16 MFMA internally.
// Round 15: k_gemm templated on MROWS. gemm<1> (out-proj) moves to 64-row
// tiles: its dense-active grid was 204 blocks for 256 CUs (<=1/CU, zero
// co-residency -> naked latency, inferred ~35us). 64-row tiles double the
// block count (~408) and cut LDS to 48KB (3/CU). gemm<0> = <0,128>, code
// identical to r13/r14. Everything else unchanged.

#define B_ 4
#define N_ 2048
#define D_ 768
#define H_ 12
#define DH_ 64
#define CSC_ 0.18033688011112042f  // SCALE * log2(e)

typedef __attribute__((ext_vector_type(8))) short bf8_t;   // 8 bf16 (MFMA A/B frag)
typedef __attribute__((ext_vector_type(4))) float f4_t;    // 16x16 C/D frag
typedef __attribute__((ext_vector_type(16))) float f16v;   // 32x32 C/D frag
typedef __attribute__((ext_vector_type(4))) int i4_t;

__device__ __forceinline__ short f2b(float f) {            // fp32 -> bf16 RNE
  union { float f; unsigned u; } v; v.f = f;
  unsigned r = v.u + 0x7FFFu + ((v.u >> 16) & 1u);
  return (short)(r >> 16);
}
__device__ __forceinline__ unsigned cvtpk(float lo, float hi) {
  unsigned r;
  asm("v_cvt_pk_bf16_f32 %0, %1, %2" : "=v"(r) : "v"(lo), "v"(hi));
  return r;
}
__device__ __forceinline__ void plswap(unsigned& a, unsigned& b) {
  asm("v_permlane32_swap_b32 %0, %1" : "+v"(a), "+v"(b));
}
__device__ __forceinline__ float max3f(float a, float b, float c) {
  float r;
  asm("v_max3_f32 %0, %1, %2, %3" : "=v"(r) : "v"(a), "v"(b), "v"(c));
  return r;
}

#define GLOAD_LDS16(gp, lp)                                                       \
  __builtin_amdgcn_global_load_lds(                                               \
      (const __attribute__((address_space(1))) void*)(gp),                        \
      (__attribute__((address_space(3))) void*)(lp), 16, 0, 0)

// ------- per-batch valid-index list + inverse perm pos[n] -------
__global__ __launch_bounds__(256) void k_maskidx(const int* __restrict__ xmask,
                                                 int* __restrict__ idx,
                                                 int* __restrict__ pos,
                                                 int* __restrict__ cnt) {
  int b = blockIdx.x, t = threadIdx.x;
  const int* mp = xmask + b * N_;
  int c = 0;
#pragma unroll
  for (int j = 0; j < 8; ++j) c += (mp[t * 8 + j] != 0);
  __shared__ int sc[256];
  sc[t] = c;
  __syncthreads();
  for (int off = 1; off < 256; off <<= 1) {
    int v = (t >= off) ? sc[t - off] : 0;
    __syncthreads();
    sc[t] += v;
    __syncthreads();
  }
  int p = sc[t] - c;
#pragma unroll
  for (int j = 0; j < 8; ++j) {
    int n = t * 8 + j;
    int v = mp[n];
    pos[b * N_ + n] = v ? p : -1;
    if (v) { idx[b * N_ + p] = n; ++p; }
  }
  if (t == 255) cnt[b] = sc[255];
}

// ------- fused: column partial-sums of x + gather valid rows -> bf16 xc -------
__global__ __launch_bounds__(256) void k_gxsum(const float* __restrict__ x,
                                               const int* __restrict__ pos,
                                               const int* __restrict__ cnt,
                                               float* __restrict__ xpart,
                                               short* __restrict__ xc) {
  int b = blockIdx.y, ch = blockIdx.x, t = threadIdx.x;
  if (ch == 64) {
    int cn = cnt[b], cnpad = (cn + 127) & ~127;
    int nel = (cnpad - cn) * D_;
    short* base = xc + ((size_t)b * N_ + cn) * D_;
    const bf8_t zz = {0, 0, 0, 0, 0, 0, 0, 0};
    for (int i = t * 8; i < nel; i += 256 * 8) *(bf8_t*)(base + i) = zz;
    return;
  }
  const float* xp = x + ((size_t)b * N_ + ch * 32) * D_;
  const int* pp = pos + b * N_ + ch * 32;
  float a0 = 0, a1 = 0, a2 = 0;
  for (int r = 0; r < 32; ++r) {
    const float* rp = xp + (size_t)r * D_;
    float v0 = rp[t], v1 = rp[t + 256], v2 = rp[t + 512];
    a0 += v0; a1 += v1; a2 += v2;
    int p = pp[r];
    if (p >= 0) {
      short* op = xc + ((size_t)b * N_ + p) * D_;
      op[t] = f2b(v0); op[t + 256] = f2b(v1); op[t + 512] = f2b(v2);
    }
  }
  float* op2 = xpart + ((size_t)b * 64 + ch) * D_;
  op2[t] = a0; op2[t + 256] = a1; op2[t + 512] = a2;
}

// ------- xmean[b][c] = (1/2048) sum_ch xpart[b][ch][c] -------
__global__ __launch_bounds__(256) void k_xmean(const float* __restrict__ xpart,
                                               float* __restrict__ xmean) {
  int b = blockIdx.y;
  int col = blockIdx.x * 64 + (threadIdx.x & 63);
  int grp = threadIdx.x >> 6;
  float s = 0;
#pragma unroll
  for (int i = 0; i < 16; ++i)
    s += xpart[((size_t)b * 64 + grp * 16 + i) * D_ + col];
  __shared__ float red[4][64];
  red[grp][threadIdx.x & 63] = s;
  __syncthreads();
  if (grp == 0) {
    int cl = threadIdx.x & 63;
    xmean[b * D_ + col] = (red[0][cl] + red[1][cl] + red[2][cl] + red[3][cl]) * (1.f / 2048.f);
  }
}

// ------- y[b][col] = sum_k xv[b][k] * W[k][col]  (split-k GEMV) -------
__global__ __launch_bounds__(256) void k_gemv(const float* __restrict__ xv,
                                              const float* __restrict__ W,
                                              float* __restrict__ y) {
  int b = blockIdx.y;
  int cl = threadIdx.x & 63;
  int col = blockIdx.x * 64 + cl;
  int grp = threadIdx.x >> 6;
  __shared__ float xs[768];
  for (int c = threadIdx.x; c < 768; c += 256) xs[c] = xv[b * D_ + c];
  __syncthreads();
  float acc = 0;
  const float* wp = W + (size_t)(grp * 192) * D_ + col;
  const float* xp = xs + grp * 192;
#pragma unroll 4
  for (int k = 0; k < 192; ++k) acc += xp[k] * wp[(size_t)k * D_];
  __shared__ float red[4][64];
  red[grp][cl] = acc;
  __syncthreads();
  if (grp == 0) y[b * D_ + col] = red[0][cl] + red[1][cl] + red[2][cl] + red[3][cl];
}

// ------- prep: transpose weights fp32->bf16 into B^T layout; Wq pre-scaled -------
__global__ __launch_bounds__(256) void k_wtrans(const float* __restrict__ Wq,
                                                const float* __restrict__ Wk,
                                                const float* __restrict__ Wv,
                                                const float* __restrict__ Wo,
                                                short* __restrict__ WqkvT,
                                                short* __restrict__ WoT) {
  int z = blockIdx.z;
  const float* W = (z == 0) ? Wq : (z == 1) ? Wk : (z == 2) ? Wv : Wo;
  short* dst = (z < 3) ? (WqkvT + (size_t)z * D_ * D_) : WoT;
  float sc = (z == 0) ? CSC_ : 1.f;
  __shared__ float T[64][65];
  int r0 = blockIdx.y * 64, c0 = blockIdx.x * 64;
  int tr = threadIdx.x >> 6, tc = threadIdx.x & 63;
#pragma unroll
  for (int i = 0; i < 16; ++i) {
    int r = tr + i * 4;
    T[r][tc] = W[(size_t)(r0 + r) * D_ + c0 + tc];
  }
  __syncthreads();
#pragma unroll
  for (int i = 0; i < 16; ++i) {
    int r = tr + i * 4;
    dst[(size_t)(c0 + r) * D_ + r0 + tc] = f2b(T[tc][r] * sc);
  }
}

// ------- GEMM: dense-active remap + col-fast m204 XCD swizzle + gload_lds dbuf.
// MROWS = row-tile height (128 for QKV GEMM, 64 for out-proj: doubles the
// active block count -> co-residency on 256 CUs). -------
template <int MODE, int MROWS>
__global__ __launch_bounds__(256) void k_gemm(const short* __restrict__ A,
                                              const short* __restrict__ BT, int K,
                                              short* __restrict__ Qb, short* __restrict__ Kb,
                                              short* __restrict__ Vb,
                                              float* __restrict__ Cout, int ldc,
                                              const int* __restrict__ cnt,
                                              const int* __restrict__ idx) {
  constexpr int MI = MROWS / 32;        // row-frags per wave (4 or 2)
  constexpr int RW = MROWS / 4;         // rows staged per wave (32 or 16)
  constexpr int SH = (MROWS == 128) ? 7 : 6;
  __shared__ short As[2][MROWS * 64];
  __shared__ short Bs[2][128 * 64];
  int n0t = (cnt[0] + MROWS - 1) >> SH, n1t = (cnt[1] + MROWS - 1) >> SH;
  int n2t = (cnt[2] + MROWS - 1) >> SH, n3t = (cnt[3] + MROWS - 1) >> SH;
  int p1 = n0t, p2 = p1 + n1t, p3 = p2 + n2t;
  int T = p3 + n3t;
  int gcols = gridDim.x;
  int Tg = T * gcols;
  int f = blockIdx.y * gcols + blockIdx.x;
  if (f >= Tg) return;
  int q = Tg >> 3, rm = Tg & 7;
  int xcd = f & 7, kch = f >> 3;
  int s = (xcd < rm ? xcd * (q + 1) : rm * (q + 1) + (xcd - rm) * q) + kch;
  int row_a = s / gcols;
  int colt = s - row_a * gcols;
  int b = (row_a >= p1) + (row_a >= p2) + (row_a >= p3);
  int pref = (b == 0) ? 0 : (b == 1) ? p1 : (b == 2) ? p2 : p3;
  int row0 = (b << 11) + ((row_a - pref) << SH);
  int col0 = colt << 7;
  int cn = cnt[b];

  int tid = threadIdx.x, lane = tid & 63, w = tid >> 6;
  int wr = w >> 1, wc = w & 1;
  int lr = lane & 15, lhi = lane >> 4;
  f4_t acc[MI][4];
#pragma unroll
  for (int mi = 0; mi < MI; ++mi)
#pragma unroll
    for (int ni = 0; ni < 4; ++ni) acc[mi][ni] = (f4_t){0.f, 0.f, 0.f, 0.f};

  int sub = lane >> 3;
  int scb = ((lane & 7) * 16) ^ (sub << 4);
  auto STAGE = [&](int k0, int buf) {
    char* ab = (char*)As[buf] + w * (RW * 128);
    char* bb2 = (char*)Bs[buf] + (w << 12);
#pragma unroll
    for (int i = 0; i < RW / 8; ++i) {
      int r = RW * w + 8 * i + sub;
      GLOAD_LDS16((const char*)(A + (size_t)(row0 + r) * K + k0) + scb, ab + (i << 10));
    }
#pragma unroll
    for (int i = 0; i < 4; ++i) {
      int r = 32 * w + 8 * i + sub;
      GLOAD_LDS16((const char*)(BT + (size_t)(col0 + r) * K + k0) + scb, bb2 + (i << 10));
    }
  };

  STAGE(0, 0);

  int nt = K / 64;
  for (int t = 0; t < nt; ++t) {
    int cur = t & 1;
    if (t + 1 < nt) {
      STAGE((t + 1) * 64, cur ^ 1);  // next-tile loads stay in flight (T4)
      if constexpr (MROWS == 128) {
        asm volatile("s_waitcnt vmcnt(8)" ::: "memory");
      } else {
        asm volatile("s_waitcnt vmcnt(6)" ::: "memory");
      }
    } else {
      asm volatile("s_waitcnt vmcnt(0)" ::: "memory");
    }
    __builtin_amdgcn_sched_barrier(0);
    __builtin_amdgcn_s_barrier();

    const char* Ac = (const char*)As[cur];
    const char* Bc = (const char*)Bs[cur];
    int rsw = (lr & 7) << 4;
#pragma unroll
    for (int kc = 0; kc < 2; ++kc) {
      bf8_t av[MI], bv[4];
#pragma unroll
      for (int mi = 0; mi < MI; ++mi) {
        int row = (MROWS / 2) * wr + 16 * mi + lr;
        av[mi] = *(const bf8_t*)(Ac + row * 128 + ((64 * kc + 16 * lhi) ^ rsw));
      }
#pragma unroll
      for (int ni = 0; ni < 4; ++ni) {
        int row = 64 * wc + 16 * ni + lr;
        bv[ni] = *(const bf8_t*)(Bc + row * 128 + ((64 * kc + 16 * lhi) ^ rsw));
      }
#pragma unroll
      for (int mi = 0; mi < MI; ++mi)
#pragma unroll
        for (int ni = 0; ni < 4; ++ni)
          acc[mi][ni] = __builtin_amdgcn_mfma_f32_16x16x32_bf16(av[mi], bv[ni], acc[mi][ni], 0, 0, 0);
    }
    __builtin_amdgcn_sched_barrier(0);
    __builtin_amdgcn_s_barrier();
  }

#pragma unroll
  for (int mi = 0; mi < MI; ++mi)
#pragma unroll
    for (int ni = 0; ni < 4; ++ni)
#pragma unroll
      for (int r = 0; r < 4; ++r) {
        int row = row0 + (MROWS / 2) * wr + 16 * mi + 4 * lhi + r;
        int col = col0 + 64 * wc + 16 * ni + lr;
        float v = acc[mi][ni][r];
        if (MODE == 0) {
          int which = col / 768;
          int cc2 = col - which * 768;
          int h = cc2 >> 6, dh = cc2 & 63;
          int bb = row >> 11, n = row & 2047;
          size_t dst = (((size_t)(bb * H_ + h)) * N_ + n) * DH_ + dh;
          short bv2 = f2b(v);
          if (which == 0) Qb[dst] = bv2;
          else if (which == 1) Kb[dst] = bv2;
          else Vb[dst] = bv2;
        } else {
          int j = row & 2047;
          if (j < cn) {
            int n = idx[(row & ~2047) + j];
            Cout[((size_t)(row & ~2047) + n) * ldc + col] = v;
          }
        }
      }
}

// ---------------- Vc[bh][j][dh] -> Vtc[bh][dh][j] (compacted) ----------------
__global__ __launch_bounds__(256) void k_vtrans(const short* __restrict__ V,
                                                const int* __restrict__ cnt,
                                                short* __restrict__ Vt) {
  int bh = blockIdx.y, b = bh / H_;
  int n0 = blockIdx.x * 64;
  int cn = cnt[b];
  int cnpad = (cn + 127) & ~127;
  if (n0 >= cnpad) return;
  __shared__ short T[64][72];
  int tr = threadIdx.x >> 6, tc = threadIdx.x & 63;
  const short* Vp = V + (size_t)bh * N_ * DH_;
  short* Vtp = Vt + (size_t)bh * DH_ * N_;
#pragma unroll
  for (int i = 0; i < 16; ++i) {
    int r = tr + i * 4;
    T[r][tc] = Vp[(size_t)(n0 + r) * DH_ + tc];
  }
  __syncthreads();
#pragma unroll
  for (int i = 0; i < 16; ++i) {
    int r = tr + i * 4;
    Vtp[(size_t)r * N_ + n0 + tc] = T[tc][r];
  }
}

// -------- fill masked rows of out with outrow[b] (fp32) --------
__global__ __launch_bounds__(256) void k_fillout(const int* __restrict__ xmask,
                                                 const float* __restrict__ outrowG,
                                                 float* __restrict__ out) {
  int b = blockIdx.y;
  int n = blockIdx.x * 32 + (threadIdx.x >> 3);
  int cg = threadIdx.x & 7;
  if (xmask[b * N_ + n]) return;
  const float* rp = outrowG + b * D_;
  float* op = out + ((size_t)b * N_ + n) * D_;
#pragma unroll
  for (int it = 0; it < 12; ++it) {
    int c = cg * 8 + it * 64;
    float4 v0 = *(const float4*)(rp + c);
    float4 v1 = *(const float4*)(rp + c + 4);
    *(float4*)(op + c) = v0;
    *(float4*)(op + c + 4) = v1;
  }
}

// -------- flash attention on compacted q/k; bh pinned to one XCD --------
__global__ __launch_bounds__(256, 3) void k_attn(const short* __restrict__ Q,
                                                 const short* __restrict__ Kcg,
                                                 const short* __restrict__ Vtcg,
                                                 const int* __restrict__ cnt,
                                                 short* __restrict__ Aout) {
  int f = blockIdx.y * gridDim.x + blockIdx.x;   // 0..767
  int xcd = f & 7, loc = f >> 3;                 // loc 0..95
  int bh = (loc >> 4) * 8 + xcd;                 // 0..47
  int qt = loc & 15;
  int b = bh / H_, h = bh - b * H_;
  int cn = cnt[b];
  int nqt = (cn + 127) >> 7;
  if (qt >= nqt) return;
  int nkt = (cn + 63) >> 6;
  const short* Qp = Q + (size_t)bh * N_ * DH_;
  const short* Kp = Kcg + (size_t)bh * N_ * DH_;
  const short* Vp = Vtcg + (size_t)bh * DH_ * N_;
  int q0 = qt * 128;
  int tid = threadIdx.x, lane = tid & 63, w = tid >> 6;
  int lq = lane & 31, hi = lane >> 5;

  __shared__ char smem[32768];

  int qrow = q0 + 32 * w + lq;

  bf8_t qf[4];
#pragma unroll
  for (int kc = 0; kc < 4; ++kc)
    qf[kc] = *(const bf8_t*)(Qp + (size_t)qrow * DH_ + 16 * kc + 8 * hi);

  short NEGBIG = f2b(-1e30f);
  bf8_t qbf = {hi ? (short)0 : (short)0x3F80, 0, 0, 0, 0, 0, 0, 0};

  f16v acco[2];
#pragma unroll
  for (int i = 0; i < 16; ++i) { acco[0][i] = 0.f; acco[1][i] = 0.f; }
  float m = -1e29f, lsum = 0.f;

  auto STAGE = [&](int key0, int buf) {
    char* kb_ = smem + buf * 16384;
    char* vb_ = kb_ + 8192;
    int row = tid >> 3;
    int cb = (tid & 7) * 16;
    char* lk = kb_ + ((tid >> 6) << 10);
    char* lv = vb_ + ((tid >> 6) << 10);
#pragma unroll
    for (int rr = 0; rr < 2; ++rr) {
      int r2 = row + rr * 32;
      int sw = cb ^ ((r2 & 7) << 4);
      GLOAD_LDS16((const char*)(Kp + (size_t)(key0 + r2) * DH_) + sw, lk + rr * 4096);
      GLOAD_LDS16((const char*)(Vp + (size_t)r2 * N_ + key0) + sw, lv + rr * 4096);
    }
  };

  STAGE(0, 0);
  __syncthreads();

  for (int kt = 0; kt < nkt; ++kt) {
    int cur = kt & 1;
    if (kt + 1 < nkt) STAGE((kt + 1) * 64, cur ^ 1);

    const char* kbase = smem + cur * 16384;
    const char* vbase = kbase + 8192;
    int key0 = kt * 64;

    f16v accs[2];
#pragma unroll
    for (int i = 0; i < 16; ++i) { accs[0][i] = 0.f; accs[1][i] = 0.f; }
    int swz = (lq & 7) << 4;
    __builtin_amdgcn_s_setprio(1);
#pragma unroll
    for (int kc = 0; kc < 4; ++kc) {
      int colb = (32 * kc + 16 * hi) ^ swz;
      bf8_t k0 = *(const bf8_t*)(kbase + lq * 128 + colb);
      bf8_t k1 = *(const bf8_t*)(kbase + (32 + lq) * 128 + colb);
      accs[0] = __builtin_amdgcn_mfma_f32_32x32x16_bf16(k0, qf[kc], accs[0], 0, 0, 0);
      accs[1] = __builtin_amdgcn_mfma_f32_32x32x16_bf16(k1, qf[kc], accs[1], 0, 0, 0);
    }
    __builtin_amdgcn_s_setprio(0);
    if (key0 + 64 > cn) {
      bf8_t bf0 = {(hi || key0 + lq < cn) ? (short)0 : NEGBIG, 0, 0, 0, 0, 0, 0, 0};
      bf8_t bf1 = {(hi || key0 + 32 + lq < cn) ? (short)0 : NEGBIG, 0, 0, 0, 0, 0, 0, 0};
      accs[0] = __builtin_amdgcn_mfma_f32_32x32x16_bf16(bf0, qbf, accs[0], 0, 0, 0);
      accs[1] = __builtin_amdgcn_mfma_f32_32x32x16_bf16(bf1, qbf, accs[1], 0, 0, 0);
    }

    float mx = max3f(accs[0][0], accs[0][1], accs[0][2]);
#pragma unroll
    for (int i = 3; i < 15; i += 2) mx = max3f(mx, accs[0][i], accs[0][i + 1]);
    mx = max3f(mx, accs[0][15], accs[1][0]);
#pragma unroll
    for (int i = 1; i < 15; i += 2) mx = max3f(mx, accs[1][i], accs[1][i + 1]);
    mx = fmaxf(mx, accs[1][15]);
    mx = fmaxf(mx, __shfl_xor(mx, 32));
    if (!__all(mx <= m + 8.f)) {
      float mnew = fmaxf(m, mx);
      float sc = __builtin_amdgcn_exp2f(m - mnew);
      m = mnew;
      lsum *= sc;
#pragma unroll
      for (int i = 0; i < 16; ++i) { acco[0][i] *= sc; acco[1][i] *= sc; }
    }
    float psa[4] = {0.f, 0.f, 0.f, 0.f};
#pragma unroll
    for (int kb2 = 0; kb2 < 2; ++kb2)
#pragma unroll
      for (int r = 0; r < 16; ++r) {
        float p = __builtin_amdgcn_exp2f(accs[kb2][r] - m);
        accs[kb2][r] = p;
        psa[r & 3] += p;
      }
    float ps = (psa[0] + psa[1]) + (psa[2] + psa[3]);
    ps += __shfl_xor(ps, 32);
    lsum += ps;

    __builtin_amdgcn_s_setprio(1);
#pragma unroll
    for (int kc = 0; kc < 4; ++kc) {
      int kb2 = kc >> 1, rb = (kc & 1) * 8;
      unsigned a_ = cvtpk(accs[kb2][rb + 0], accs[kb2][rb + 1]);
      unsigned b_ = cvtpk(accs[kb2][rb + 4], accs[kb2][rb + 5]);
      unsigned c_ = cvtpk(accs[kb2][rb + 2], accs[kb2][rb + 3]);
      unsigned d_ = cvtpk(accs[kb2][rb + 6], accs[kb2][rb + 7]);
      plswap(a_, b_);
      plswap(c_, d_);
      union { i4_t i; bf8_t v; } pu;
      pu.i = (i4_t){(int)a_, (int)c_, (int)b_, (int)d_};
      int colb = (32 * kc + 16 * hi) ^ swz;
      bf8_t v0 = *(const bf8_t*)(vbase + lq * 128 + colb);
      bf8_t v1 = *(const bf8_t*)(vbase + (32 + lq) * 128 + colb);
      acco[0] = __builtin_amdgcn_mfma_f32_32x32x16_bf16(v0, pu.v, acco[0], 0, 0, 0);
      acco[1] = __builtin_amdgcn_mfma_f32_32x32x16_bf16(v1, pu.v, acco[1], 0, 0, 0);
    }
    __builtin_amdgcn_s_setprio(0);

    __syncthreads();
  }
  __syncthreads();

  float inv = 1.f / lsum;
  unsigned* Os = (unsigned*)smem + w * 1152;
#pragma unroll
  for (int dhb = 0; dhb < 2; ++dhb)
#pragma unroll
    for (int r = 0; r < 16; r += 2) {
      unsigned pk = cvtpk(acco[dhb][r] * inv, acco[dhb][r + 1] * inv);
      int colu = 16 * dhb + ((r & 3) >> 1) + 4 * (r >> 2) + 2 * hi;
      Os[lq * 36 + colu] = pk;
    }
#pragma unroll
  for (int it = 0; it < 4; ++it) {
    int qq = (lane >> 3) + 8 * it;
    int qr2 = q0 + 32 * w + qq;
    if (qr2 < cn) {
      i4_t vv = *(const i4_t*)(Os + qq * 36 + 4 * (lane & 7));
      union { i4_t i; bf8_t s; } u2;
      u2.i = vv;
      size_t off = ((size_t)b * N_ + qr2) * D_ + h * DH_ + 8 * (lane & 7);
      *(bf8_t*)(Aout + off) = u2.s;
    }
  }
}

extern "C" void kernel_launch(void* const* d_in, const int* in_sizes, int n_in,
                              void* d_out, int out_size, void* d_ws, size_t ws_size,
                              hipStream_t stream) {
  (void)in_sizes; (void)n_in; (void)out_size; (void)ws_size;
  const float* x  = (const float*)d_in[0];
  const int*   xm = (const int*)d_in[1];
  const float* Wq = (const float*)d_in[2];
  const float* Wk = (const float*)d_in[3];
  const float* Wv = (const float*)d_in[4];
  const float* Wo = (const float*)d_in[5];
  float* out = (float*)d_out;
  char* ws = (char*)d_ws;

  short* xc      = (short*)(ws + 0);
  short* Ao      = (short*)(ws + 0);
  short* WqkvT   = (short*)(ws + 12582912);
  short* WoT     = (short*)(ws + 16121856);
  int*   idxb    = (int*)(ws + 17301504);
  int*   cntb    = (int*)(ws + 17334272);
  float* xpart   = (float*)(ws + 17334528);
  float* vmeanG  = (float*)(ws + 18120960);
  float* outrowG = (float*)(ws + 18133248);
  float* xmeanG  = (float*)(ws + 18145536);
  int*   posb    = (int*)(ws + 18157824);
  short* Qb      = (short*)(ws + 18874368);
  short* Kc      = (short*)(ws + 31457280);
  short* Vc      = (short*)(ws + 44040192);
  short* Vtc     = (short*)(ws + 56623104);

  k_maskidx<<<4, 256, 0, stream>>>(xm, idxb, posb, cntb);
  k_gxsum<<<dim3(65, 4), 256, 0, stream>>>(x, posb, cntb, xpart, xc);
  k_wtrans<<<dim3(12, 12, 4), 256, 0, stream>>>(Wq, Wk, Wv, Wo, WqkvT, WoT);
  k_gemm<0, 128><<<dim3(18, 64), 256, 0, stream>>>(xc, WqkvT, 768, Qb, Kc, Vc,
                                                   nullptr, 0, cntb, nullptr);
  k_vtrans<<<dim3(32, 48), 256, 0, stream>>>(Vc, cntb, Vtc);
  k_xmean<<<dim3(12, 4), 256, 0, stream>>>(xpart, xmeanG);
  k_gemv<<<dim3(12, 4), 256, 0, stream>>>(xmeanG, Wv, vmeanG);
  k_gemv<<<dim3(12, 4), 256, 0, stream>>>(vmeanG, Wo, outrowG);
  k_attn<<<dim3(16, 48), 256, 0, stream>>>(Qb, Kc, Vtc, cntb, Ao);
  k_fillout<<<dim3(64, 4), 256, 0, stream>>>(xm, outrowG, out);
  k_gemm<1, 64><<<dim3(6, 128), 256, 0, stream>>>(Ao, WoT, 768, nullptr, nullptr, nullptr,
                                                  out, 768, cntb, idxb);
}